// Round 1
// baseline (514.625 us; speedup 1.0000x reference)
//
#include <hip/hip_runtime.h>

// Router: x = token_inputs * jitter; logits = x @ w + b; softmax over E=64;
// keep top-2 probs, zero the rest. Tokens = 32768, H = 2048, E = 64. All fp32.
//
// Block = 256 threads (4 waves) owns 64 tokens. K-split by 4 across waves
// (wave w handles k in [w*512, w*512+512)). Lane = token; each lane holds 64
// fp32 expert accumulators. w[k][e] is wave-uniform -> scalar loads feeding
// v_fmac. x*jitter staged coalesced into wave-private LDS chunks.

#define H       2048
#define E       64
#define KSPLIT  4
#define KC      (H / KSPLIT)    // 512 per wave
#define KCHUNK  64              // k's staged per step
#define NSTEP   (KC / KCHUNK)   // 8
#define LDS_PAD 68              // 64 + 4: keeps float4 alignment, spreads banks

__global__ __launch_bounds__(256, 2)
void router_kernel(const float* __restrict__ x,
                   const float* __restrict__ jit,
                   const float* __restrict__ w,
                   const float* __restrict__ bias,
                   float* __restrict__ out)
{
    // Wave-private staging; reused as K-split reduction buffer afterwards.
    __shared__ float stage[KSPLIT][64][LDS_PAD];

    const int tid  = threadIdx.x;
    const int wave = tid >> 6;
    const int lane = tid & 63;

    const size_t blockTok = (size_t)blockIdx.x * 64;
    const int    k0       = wave * KC;

    float acc[E];
#pragma unroll
    for (int e = 0; e < E; ++e) acc[e] = 0.0f;

    // cooperative-staging coordinates: 4 rows x 256B per instruction
    const int srow = lane >> 4;         // 0..3
    const int scol = (lane & 15) << 2;  // 0,4,...,60

    for (int s = 0; s < NSTEP; ++s) {
        const int kbase = k0 + s * KCHUNK;

        // ---- stage 64 tokens x KCHUNK of (x * jitter) into LDS (coalesced) ----
#pragma unroll
        for (int rr = 0; rr < 16; ++rr) {
            const int    row = rr * 4 + srow;
            const size_t g   = (blockTok + row) * H + (size_t)(kbase + scol);
            const float4 xv  = *reinterpret_cast<const float4*>(x + g);
            const float4 jv  = *reinterpret_cast<const float4*>(jit + g);
            float4 v;
            v.x = xv.x * jv.x; v.y = xv.y * jv.y;
            v.z = xv.z * jv.z; v.w = xv.w * jv.w;
            *reinterpret_cast<float4*>(&stage[wave][row][scol]) = v;
        }
        // no barrier: stage[wave] is wave-private; compiler inserts lgkmcnt waits

        // ---- FMA sweep: lane = token, 64 expert accumulators ----
        for (int kk = 0; kk < KCHUNK; kk += 4) {
            const float4 xs = *reinterpret_cast<const float4*>(&stage[wave][lane][kk]);
            const float* wp = w + (size_t)(kbase + kk) * E;   // wave-uniform
#pragma unroll
            for (int e = 0; e < E; ++e) acc[e] = fmaf(xs.x, wp[e],         acc[e]);
#pragma unroll
            for (int e = 0; e < E; ++e) acc[e] = fmaf(xs.y, wp[E + e],     acc[e]);
#pragma unroll
            for (int e = 0; e < E; ++e) acc[e] = fmaf(xs.z, wp[2 * E + e], acc[e]);
#pragma unroll
            for (int e = 0; e < E; ++e) acc[e] = fmaf(xs.w, wp[3 * E + e], acc[e]);
        }
    }

    // ---- write partial logits into LDS (reuse stage as reduction buffer) ----
#pragma unroll
    for (int e0 = 0; e0 < E; e0 += 4) {
        float4 v;
        v.x = acc[e0]; v.y = acc[e0 + 1]; v.z = acc[e0 + 2]; v.w = acc[e0 + 3];
        *reinterpret_cast<float4*>(&stage[wave][lane][e0]) = v;
    }
    __syncthreads();

    // ---- wave 0: reduce K-split partials, softmax, top-2 mask ----
    if (wave == 0) {
        const int t = lane;
        float l[E];
        float m = -3.0e38f;
#pragma unroll
        for (int e0 = 0; e0 < E; e0 += 4) {
            const float4 a0 = *reinterpret_cast<const float4*>(&stage[0][t][e0]);
            const float4 a1 = *reinterpret_cast<const float4*>(&stage[1][t][e0]);
            const float4 a2 = *reinterpret_cast<const float4*>(&stage[2][t][e0]);
            const float4 a3 = *reinterpret_cast<const float4*>(&stage[3][t][e0]);
            const float v0 = a0.x + a1.x + a2.x + a3.x + bias[e0 + 0];
            const float v1 = a0.y + a1.y + a2.y + a3.y + bias[e0 + 1];
            const float v2 = a0.z + a1.z + a2.z + a3.z + bias[e0 + 2];
            const float v3 = a0.w + a1.w + a2.w + a3.w + bias[e0 + 3];
            l[e0 + 0] = v0; l[e0 + 1] = v1; l[e0 + 2] = v2; l[e0 + 3] = v3;
            m = fmaxf(m, fmaxf(fmaxf(v0, v1), fmaxf(v2, v3)));
        }

        float ssum = 0.0f;
#pragma unroll
        for (int e = 0; e < E; ++e) {
            const float p = __expf(l[e] - m);
            l[e] = p;
            ssum += p;
        }
        const float inv = 1.0f / ssum;

        // top-2 scan (ascending e, strict > keeps lowest index on ties,
        // matching jax.lax.top_k)
        float p1 = -1.0f, p2 = -1.0f;
        int   i1 = 0,     i2 = 0;
#pragma unroll
        for (int e = 0; e < E; ++e) {
            const float p = l[e] * inv;
            l[e] = p;
            if (p > p1)      { p2 = p1; i2 = i1; p1 = p; i1 = e; }
            else if (p > p2) { p2 = p;  i2 = e; }
        }

#pragma unroll
        for (int e0 = 0; e0 < E; e0 += 4) {
            float4 v;
            v.x = (e0 + 0 == i1 || e0 + 0 == i2) ? l[e0 + 0] : 0.0f;
            v.y = (e0 + 1 == i1 || e0 + 1 == i2) ? l[e0 + 1] : 0.0f;
            v.z = (e0 + 2 == i1 || e0 + 2 == i2) ? l[e0 + 2] : 0.0f;
            v.w = (e0 + 3 == i1 || e0 + 3 == i2) ? l[e0 + 3] : 0.0f;
            *reinterpret_cast<float4*>(&stage[0][t][e0]) = v;
        }
    }
    __syncthreads();

    // ---- coalesced output store: 64 tokens x 64 experts = 16 KB ----
    float* outp = out + blockTok * E;
#pragma unroll
    for (int i = tid; i < 64 * E / 4; i += 256) {
        const int t  = i >> 4;
        const int e0 = (i & 15) << 2;
        *reinterpret_cast<float4*>(outp + (size_t)t * E + e0) =
            *reinterpret_cast<const float4*>(&stage[0][t][e0]);
    }
}

extern "C" void kernel_launch(void* const* d_in, const int* in_sizes, int n_in,
                              void* d_out, int out_size, void* d_ws, size_t ws_size,
                              hipStream_t stream)
{
    const float* x   = (const float*)d_in[0];
    const float* jit = (const float*)d_in[1];
    const float* w   = (const float*)d_in[2];
    const float* b   = (const float*)d_in[3];
    float*       out = (float*)d_out;

    const int n_tok = in_sizes[0] / H;   // 32768
    dim3 grid(n_tok / 64), block(256);
    hipLaunchKernelGGL(router_kernel, grid, block, 0, stream, x, jit, w, b, out);
}

// Round 2
// 287.744 us; speedup vs baseline: 1.7885x; 1.7885x over previous
//
#include <hip/hip_runtime.h>

// MoE router, fp32: x = token_inputs * jitter; logits = x @ w + b;
// softmax over E=64; keep top-2 probs, zero rest.
// Tokens = 32768, H = 2048, E = 64.
//
// Expert-split design: block = 512 threads (8 waves), 64 tokens/block.
// Wave w computes experts [8w, 8w+8) over the FULL k range -> acc[8]/lane.
// w loads are wave-uniform via readfirstlane -> scalar s_load on the SMEM
// pipe (no VGPR cost, no VALU contention). x*jitter is staged transposed
// (xs[k][t], XOR-swizzled) so compute reads are lane-linear conflict-free.

#define H        2048
#define E        64
#define TOKB     64
#define NWAVE    8
#define EPW      8                // experts per wave
#define KCHUNK   64
#define NCHUNK   (H / KCHUNK)     // 32

__global__ __launch_bounds__(512, 4)
void router_kernel(const float* __restrict__ xg,
                   const float* __restrict__ jg,
                   const float* __restrict__ wg,
                   const float* __restrict__ bias,
                   float* __restrict__ out)
{
    // transposed + swizzled staging: element (k,t) lives at xs[buf][k][t ^ (k & 60)]
    __shared__ float xs[2][KCHUNK][TOKB];   // 32 KB
    // transposed + swizzled logits: (e,t) lives at lg[e][t ^ e]
    __shared__ float lg[E][TOKB];           // 16 KB

    const float* w = (const float*)__builtin_assume_aligned(wg, 256);

    const int tid  = threadIdx.x;
    const int wave = tid >> 6;
    const int lane = tid & 63;
    const size_t blockTok = (size_t)blockIdx.x * TOKB;

    // staging map: thread handles float4 columns sc (16B col) of token rows
    // st0 and st0+32. Consecutive lanes -> consecutive 16B -> coalesced.
    const int st0 = tid >> 4;               // 0..31
    const int sc  = tid & 15;               // 0..15
    const size_t g0 = (blockTok + st0)      * (size_t)H + (size_t)sc * 4;
    const size_t g1 = (blockTok + st0 + 32) * (size_t)H + (size_t)sc * 4;

    // wave-uniform expert base -> scalar loads of w
    const int e0u = __builtin_amdgcn_readfirstlane(wave * EPW);

    float acc[EPW];
#pragma unroll
    for (int e = 0; e < EPW; ++e) acc[e] = 0.f;

    float4 xa, ja, xb, jb;

    // ---- prologue: load + stage chunk 0 ----
    xa = *(const float4*)(xg + g0);
    ja = *(const float4*)(jg + g0);
    xb = *(const float4*)(xg + g1);
    jb = *(const float4*)(jg + g1);
    {
        const int kb   = sc * 4;
        const int colA = st0 ^ kb;          // kb & 60 == kb (kb multiple of 4)
        const int colB = (st0 + 32) ^ kb;
        xs[0][kb + 0][colA] = xa.x * ja.x;
        xs[0][kb + 1][colA] = xa.y * ja.y;
        xs[0][kb + 2][colA] = xa.z * ja.z;
        xs[0][kb + 3][colA] = xa.w * ja.w;
        xs[0][kb + 0][colB] = xb.x * jb.x;
        xs[0][kb + 1][colB] = xb.y * jb.y;
        xs[0][kb + 2][colB] = xb.z * jb.z;
        xs[0][kb + 3][colB] = xb.w * jb.w;
    }
    __syncthreads();

    // ---- main loop over K chunks ----
    for (int c = 0; c < NCHUNK; ++c) {
        const int buf = c & 1;

        // issue next chunk's global loads EARLY; latency hides under FMAs
        if (c + 1 < NCHUNK) {
            const size_t off = (size_t)(c + 1) * KCHUNK;
            xa = *(const float4*)(xg + g0 + off);
            ja = *(const float4*)(jg + g0 + off);
            xb = *(const float4*)(xg + g1 + off);
            jb = *(const float4*)(jg + g1 + off);
        }

        // FMA sweep: lane = token, 8 expert accumulators, scalar w operands
        const float* wrow = w + (size_t)c * KCHUNK * E + e0u;
#pragma unroll
        for (int k = 0; k < KCHUNK; ++k) {
            const float xv = xs[buf][k][lane ^ (k & 60)];
            const float* wp = wrow + (size_t)k * E;     // uniform -> s_load
#pragma unroll
            for (int e = 0; e < EPW; ++e)
                acc[e] = fmaf(xv, wp[e], acc[e]);
        }
        __syncthreads();

        // write next chunk into the other buffer
        if (c + 1 < NCHUNK) {
            const int kb   = sc * 4;
            const int colA = st0 ^ kb;
            const int colB = (st0 + 32) ^ kb;
            const int nb   = buf ^ 1;
            xs[nb][kb + 0][colA] = xa.x * ja.x;
            xs[nb][kb + 1][colA] = xa.y * ja.y;
            xs[nb][kb + 2][colA] = xa.z * ja.z;
            xs[nb][kb + 3][colA] = xa.w * ja.w;
            xs[nb][kb + 0][colB] = xb.x * jb.x;
            xs[nb][kb + 1][colB] = xb.y * jb.y;
            xs[nb][kb + 2][colB] = xb.z * jb.z;
            xs[nb][kb + 3][colB] = xb.w * jb.w;
        }
        __syncthreads();
    }

    // ---- exchange logits via LDS (transposed, swizzled) ----
#pragma unroll
    for (int e = 0; e < EPW; ++e) {
        const int eg = e0u + e;
        lg[eg][lane ^ eg] = acc[e];
    }
    __syncthreads();

    // ---- wave 0: softmax + top-2 (lane = token) ----
    if (wave == 0) {
        const int t = lane;
        // pass 1: max and top-2 on logits (+bias). exp is monotone, so
        // top-2 of logits == top-2 of probs; strict '>' ascending keeps
        // the lowest index on ties (matches jax.lax.top_k stability).
        float l1 = -3.0e38f, l2 = -3.0e38f;
        int   i1 = 0,        i2 = 0;
#pragma unroll
        for (int e = 0; e < E; ++e) {
            const float v = lg[e][t ^ e] + bias[e];
            if (v > l1)      { l2 = l1; i2 = i1; l1 = v; i1 = e; }
            else if (v > l2) { l2 = v;  i2 = e; }
        }
        const float m = l1;
        // pass 2: sum of exp
        float s = 0.f;
#pragma unroll
        for (int e = 0; e < E; ++e) {
            const float v = lg[e][t ^ e] + bias[e];
            s += __expf(v - m);
        }
        const float inv = 1.f / s;
        // zero-fill, then write the two kept probs (dynamic LDS writes)
#pragma unroll
        for (int e = 0; e < E; ++e) lg[e][t ^ e] = 0.f;
        lg[i1][t ^ i1] = inv;                     // exp(0) * inv
        lg[i2][t ^ i2] = __expf(l2 - m) * inv;
    }
    __syncthreads();

    // ---- coalesced output store: 64 tok x 64 e = 16 KB ----
#pragma unroll
    for (int h = 0; h < 2; ++h) {
        const int t  = st0 + h * 32;
        const int eb = sc * 4;
        float4 v;
        v.x = lg[eb + 0][t ^ (eb + 0)];
        v.y = lg[eb + 1][t ^ (eb + 1)];
        v.z = lg[eb + 2][t ^ (eb + 2)];
        v.w = lg[eb + 3][t ^ (eb + 3)];
        *(float4*)(out + (blockTok + t) * (size_t)E + eb) = v;
    }
}

extern "C" void kernel_launch(void* const* d_in, const int* in_sizes, int n_in,
                              void* d_out, int out_size, void* d_ws, size_t ws_size,
                              hipStream_t stream)
{
    const float* x   = (const float*)d_in[0];
    const float* jit = (const float*)d_in[1];
    const float* w   = (const float*)d_in[2];
    const float* b   = (const float*)d_in[3];
    float*       out = (float*)d_out;

    const int n_tok = in_sizes[0] / H;     // 32768
    dim3 grid(n_tok / TOKB), block(NWAVE * 64);
    hipLaunchKernelGGL(router_kernel, grid, block, 0, stream, x, jit, w, b, out);
}

// Round 3
// 203.973 us; speedup vs baseline: 2.5230x; 1.4107x over previous
//
#include <hip/hip_runtime.h>

// MoE router, fp32: x = token_inputs * jitter; logits = x @ w + b;
// softmax over E=64; keep top-2 probs, zero rest. Tokens=32768, H=2048, E=64.
//
// Block = 512 threads (8 waves), 64 tokens. Wave w owns experts [8w,8w+8).
// BOTH x and w chunks live in LDS (double-buffered). Inner loop reads:
//   xv  : per-lane ds_read_b32 from transposed+swizzled xs (conflict-free)
//   w   : uniform-address ds_read_b128 x2 (broadcast, conflict-free)
// -> zero SMEM in the loop, so no lgkmcnt(0) out-of-order drains; DS is
// in-order and the compiler can interleave fine-grained lgkmcnt waits.
// One barrier per chunk. Parallel shfl-based softmax/top-2 epilogue.

#define H        2048
#define E        64
#define TOKB     64
#define EPW      8
#define KCHUNK   64
#define NCHUNK   (H / KCHUNK)   // 32

__global__ __launch_bounds__(512, 4)
void router_kernel(const float* __restrict__ xg,
                   const float* __restrict__ jg,
                   const float* __restrict__ wg,
                   const float* __restrict__ bias,
                   float* __restrict__ out)
{
    // x*jitter transposed: element (k,t) at xs[b][k][t ^ (k&60)]
    __shared__ __align__(16) float xs[2][KCHUNK][TOKB];   // 32 KB
    // w chunk, linear row-major [k][e]
    __shared__ __align__(16) float ws[2][KCHUNK * E];     // 32 KB

    const int tid  = threadIdx.x;
    const int wave = tid >> 6;
    const int lane = tid & 63;
    const size_t blockTok = (size_t)blockIdx.x * TOKB;

    // x staging map: thread covers float4 col kb of token rows st0, st0+32
    const int st0 = tid >> 4;            // 0..31
    const int sc  = tid & 15;            // 0..15
    const int kb  = sc << 2;             // 0..60
    const size_t g0 = (blockTok + st0)      * (size_t)H + kb;
    const size_t g1 = (blockTok + st0 + 32) * (size_t)H + kb;
    const int colA = st0 ^ kb;
    const int colB = (st0 + 32) ^ kb;
    // w staging map: thread covers floats [8*tid, 8*tid+8) of the 4096-float chunk
    const int wf = tid << 3;

    const int e0 = wave * EPW;

    float acc[EPW];
#pragma unroll
    for (int i = 0; i < EPW; ++i) acc[i] = 0.f;

    float4 xa, ja, xb, jb, wa, wb;

#define LOAD_CHUNK(c) do {                                        \
        const size_t xo = (size_t)(c) * KCHUNK;                   \
        xa = *(const float4*)(xg + g0 + xo);                      \
        ja = *(const float4*)(jg + g0 + xo);                      \
        xb = *(const float4*)(xg + g1 + xo);                      \
        jb = *(const float4*)(jg + g1 + xo);                      \
        const float* wp_ = wg + (size_t)(c) * (KCHUNK * E) + wf;  \
        wa = *(const float4*)wp_;                                 \
        wb = *(const float4*)(wp_ + 4);                           \
    } while (0)

#define STAGE_CHUNK(b) do {                                       \
        xs[b][kb + 0][colA] = xa.x * ja.x;                        \
        xs[b][kb + 1][colA] = xa.y * ja.y;                        \
        xs[b][kb + 2][colA] = xa.z * ja.z;                        \
        xs[b][kb + 3][colA] = xa.w * ja.w;                        \
        xs[b][kb + 0][colB] = xb.x * jb.x;                        \
        xs[b][kb + 1][colB] = xb.y * jb.y;                        \
        xs[b][kb + 2][colB] = xb.z * jb.z;                        \
        xs[b][kb + 3][colB] = xb.w * jb.w;                        \
        *(float4*)(&ws[b][wf])     = wa;                          \
        *(float4*)(&ws[b][wf + 4]) = wb;                          \
    } while (0)

    // prologue: chunk 0 -> LDS buf0; chunk 1 -> regs
    LOAD_CHUNK(0);
    STAGE_CHUNK(0);
    LOAD_CHUNK(1);
    __syncthreads();

    for (int c = 0; c < NCHUNK; ++c) {
        const int buf = c & 1;
        const int nb  = buf ^ 1;

        // stage chunk c+1 from regs into the idle buffer (safe: all waves
        // passed the previous barrier, so nobody still reads buffer nb)
        if (c + 1 < NCHUNK) STAGE_CHUNK(nb);
        // issue chunk c+2 global loads; they land by the end-of-iter barrier
        if (c + 2 < NCHUNK) LOAD_CHUNK(c + 2);

        // FMA sweep: lane = token, 8 expert accs, W via uniform broadcast
        const float* wsb = &ws[buf][e0];
#pragma unroll
        for (int k = 0; k < KCHUNK; ++k) {
            const float  xv = xs[buf][k][lane ^ (k & 60)];
            const float4 w0 = *(const float4*)(wsb + k * E);
            const float4 w1 = *(const float4*)(wsb + k * E + 4);
            acc[0] = fmaf(xv, w0.x, acc[0]);
            acc[1] = fmaf(xv, w0.y, acc[1]);
            acc[2] = fmaf(xv, w0.z, acc[2]);
            acc[3] = fmaf(xv, w0.w, acc[3]);
            acc[4] = fmaf(xv, w1.x, acc[4]);
            acc[5] = fmaf(xv, w1.y, acc[5]);
            acc[6] = fmaf(xv, w1.z, acc[6]);
            acc[7] = fmaf(xv, w1.w, acc[7]);
        }
        __syncthreads();
    }

    // ---- exchange logits via LDS (overlay on xs[0]): (e,t) at lg[e][t^e] ----
    float (*lg)[TOKB] = (float (*)[TOKB])&xs[0][0][0];
#pragma unroll
    for (int i = 0; i < EPW; ++i) {
        const int e = e0 + i;
        lg[e][lane ^ e] = acc[i];
    }
    __syncthreads();

    // ---- parallel softmax + top-2: 8 threads per token ----
    const int t  = (wave << 3) + (lane >> 3);   // token within block
    const int eb = (lane & 7) << 3;             // this thread's 8 experts

    const float4 b0 = *(const float4*)(bias + eb);
    const float4 b1 = *(const float4*)(bias + eb + 4);
    float l[8];
#pragma unroll
    for (int i = 0; i < 8; ++i) {
        const int e = eb + i;
        l[i] = lg[e][t ^ e];
    }
    l[0] += b0.x; l[1] += b0.y; l[2] += b0.z; l[3] += b0.w;
    l[4] += b1.x; l[5] += b1.y; l[6] += b1.z; l[7] += b1.w;

    // local top-2 over the 8 logits (strict '>' keeps lowest index on ties)
    float p1 = l[0]; int i1 = eb;
    float p2 = -3.0e38f; int i2 = eb;
#pragma unroll
    for (int i = 1; i < 8; ++i) {
        if (l[i] > p1)      { p2 = p1; i2 = i1; p1 = l[i]; i1 = eb + i; }
        else if (l[i] > p2) { p2 = l[i]; i2 = eb + i; }
    }

    // butterfly merge across the token's 8 threads (lanes s*8..s*8+7)
#pragma unroll
    for (int m = 1; m <= 4; m <<= 1) {
        const float q1 = __shfl_xor(p1, m, 8);
        const int   k1 = __shfl_xor(i1, m, 8);
        const float q2 = __shfl_xor(p2, m, 8);
        const int   k2 = __shfl_xor(i2, m, 8);
        const bool  bw = (q1 > p1) || (q1 == p1 && k1 < i1);
        const float f1 = bw ? q1 : p1;  const int fi1 = bw ? k1 : i1;
        const float lo = bw ? p1 : q1;  const int loi = bw ? i1 : k1;
        const float sn = bw ? q2 : p2;  const int sni = bw ? k2 : i2;
        const bool  rw = (lo > sn) || (lo == sn && loi < sni);
        p2 = rw ? lo : sn;  i2 = rw ? loi : sni;
        p1 = f1;            i1 = fi1;
    }
    // p1 == global max logit (top-1), p2 == second

    // denominator: sum over all 64 experts of exp(l - max)
    float d = 0.f;
#pragma unroll
    for (int i = 0; i < 8; ++i) d += __expf(l[i] - p1);
#pragma unroll
    for (int m = 1; m <= 4; m <<= 1) d += __shfl_xor(d, m, 8);

    const float inv = 1.f / d;                 // prob of top-1
    const float v2  = __expf(p2 - p1) * inv;   // prob of top-2

    float o[8];
#pragma unroll
    for (int i = 0; i < 8; ++i) {
        const int e = eb + i;
        o[i] = (e == i1) ? inv : (e == i2) ? v2 : 0.f;
    }
    float* op = out + (blockTok + t) * (size_t)E + eb;
    float4 v0; v0.x = o[0]; v0.y = o[1]; v0.z = o[2]; v0.w = o[3];
    float4 v1; v1.x = o[4]; v1.y = o[5]; v1.z = o[6]; v1.w = o[7];
    *(float4*)op       = v0;
    *(float4*)(op + 4) = v1;
}

extern "C" void kernel_launch(void* const* d_in, const int* in_sizes, int n_in,
                              void* d_out, int out_size, void* d_ws, size_t ws_size,
                              hipStream_t stream)
{
    const float* x   = (const float*)d_in[0];
    const float* jit = (const float*)d_in[1];
    const float* w   = (const float*)d_in[2];
    const float* b   = (const float*)d_in[3];
    float*       out = (float*)d_out;

    const int n_tok = in_sizes[0] / H;     // 32768
    dim3 grid(n_tok / TOKB), block(512);
    hipLaunchKernelGGL(router_kernel, grid, block, 0, stream, x, jit, w, b, out);
}